// Round 1
// baseline (73.903 us; speedup 1.0000x reference)
//
#include <hip/hip_runtime.h>
#include <stdint.h>

#define D_IN    2048
#define NT      15
#define PPT     14359      // 7*(2048+1) + 8*2
#define NVALID  60         // 15 trees * 4 used internal nodes
#define NITER   32         // K = 2048 = 32 iters * BK 64
#define SLAB    16384      // bytes of B (hi+lo) per iter: 64k * 64col... = 2*8192
#define BM      64

typedef __bf16   bf16x8 __attribute__((ext_vector_type(8)));
typedef float    f32x4  __attribute__((ext_vector_type(4)));
typedef uint32_t u32x4  __attribute__((ext_vector_type(4)));

// ---------------- prep: split W into bf16 hi/lo in MFMA-B fragment order ----
// W[n][k], n = t*4+i (i = internal node 0..3 only; nodes 4..6 never reach output)
// frag element (ks,f,part): lane l, elem j  <-  W[16f + (l&15)][32ks + 8*(l>>4) + j]
__global__ __launch_bounds__(256) void prep_split(const float* __restrict__ tp,
                                                  unsigned short* __restrict__ bsp) {
  int id = blockIdx.x * 256 + threadIdx.x;   // [0, 64*2048)
  int n = id >> 11;
  int k = id & 2047;
  float v = 0.0f;
  if (n < NVALID) {
    int t = n >> 2, i = n & 3;
    v = tp[t * PPT + i * D_IN + k];
  }
  uint32_t u  = __float_as_uint(v);
  uint32_t hm = u & 0xFFFF0000u;             // truncated-bf16 hi (residual catches the rest)
  float    lo = v - __uint_as_float(hm);
  uint32_t lu = __float_as_uint(lo);
  int ks = k >> 5, f = n >> 4;
  int lane = (n & 15) | (((k >> 3) & 3) << 4);
  int j = k & 7;
  size_t base = ((size_t)(ks * 4 + f) * 2) * 512 + (size_t)lane * 8 + j;
  bsp[base]       = (unsigned short)(u  >> 16);   // part 0 = hi
  bsp[base + 512] = (unsigned short)(lu >> 16);   // part 1 = lo
}

// ---------------- prep: per-tree coefficients --------------------------------
// lp = [1, d0, 1-d0, d1, 1-d1, d2, 1-d2, d3] / (4 + d3 + 1e-8)
// out_c = w/(4+d3+eps) * (base_c + d0*a0c + d1*a1c + d2*a2c + d3*a3c)
__global__ void prep_coef(const float* __restrict__ tp, const float* __restrict__ tw,
                          float* __restrict__ bias, float* __restrict__ coef) {
  int tid = threadIdx.x;
  if (tid < 64) {
    float b = 0.0f;
    if (tid < NVALID) { int t = tid >> 2, i = tid & 3; b = tp[t * PPT + 14336 + i]; }
    bias[tid] = b;
  }
  if (tid < NT) {
    int t = tid;
    const float* ll = tp + t * PPT + 14343;  // leaf_logits [8][2]
    float d0[8], d1[8];
#pragma unroll
    for (int le = 0; le < 8; ++le) {
      float aa = ll[2 * le], bb = ll[2 * le + 1];
      float m = fmaxf(aa, bb);
      float e0 = __expf(aa - m), e1 = __expf(bb - m);
      float inv = 1.0f / (e0 + e1);
      d0[le] = e0 * inv; d1[le] = e1 * inv;
    }
    float w = tw[t];
    float* c = coef + t * 10;
    c[0] = w * (d0[0] + d0[2] + d0[4] + d0[6]);
    c[1] = w * (d1[0] + d1[2] + d1[4] + d1[6]);
    c[2] = w * (d0[1] - d0[2]);
    c[3] = w * (d1[1] - d1[2]);
    c[4] = w * (d0[3] - d0[4]);
    c[5] = w * (d1[3] - d1[4]);
    c[6] = w * (d0[5] - d0[6]);
    c[7] = w * (d1[5] - d1[6]);
    c[8] = w * d0[7];
    c[9] = w * d1[7];
  }
}

// ---------------- main fused kernel ------------------------------------------
__device__ __forceinline__ bf16x8 ldfrag(const unsigned char* p) {
  u32x4 r = *(const u32x4*)p;
  return __builtin_bit_cast(bf16x8, r);
}

#define CVT_PAIR(P, Q, HW, LW) do {                                   \
    uint32_t _up = __float_as_uint(P), _uq = __float_as_uint(Q);      \
    uint32_t _mp = _up & 0xFFFF0000u, _mq = _uq & 0xFFFF0000u;        \
    (HW) = (_up >> 16) | _mq;                                         \
    float _lp = (P) - __uint_as_float(_mp);                           \
    float _lq = (Q) - __uint_as_float(_mq);                           \
    (LW) = (__float_as_uint(_lp) >> 16) |                             \
           (__float_as_uint(_lq) & 0xFFFF0000u);                      \
  } while (0)

__device__ __forceinline__ void cvt_hilo(const float4 A, const float4 B,
                                         bf16x8& hi, bf16x8& lo) {
  u32x4 hw, lw;
  CVT_PAIR(A.x, A.y, hw[0], lw[0]);
  CVT_PAIR(A.z, A.w, hw[1], lw[1]);
  CVT_PAIR(B.x, B.y, hw[2], lw[2]);
  CVT_PAIR(B.z, B.w, hw[3], lw[3]);
  hi = __builtin_bit_cast(bf16x8, hw);
  lo = __builtin_bit_cast(bf16x8, lw);
}

__global__ __launch_bounds__(256, 2) void tree_fused(
    const float* __restrict__ x,
    const unsigned short* __restrict__ bsp,
    const float* __restrict__ bias,
    const float* __restrict__ coef,
    float* __restrict__ out)
{
  __shared__ unsigned char sB[2][SLAB];      // B hi/lo double buffer
  __shared__ float strips[4][16][65];        // per-wave epilogue strip (pad 65)

  const int tid = threadIdx.x;
  const int w   = tid >> 6;        // wave 0..3
  const int l   = tid & 63;
  const int rl  = l & 15;
  const int g   = l >> 4;

  const int rowTile = blockIdx.x * BM + w * 16;
  const float* xrow = x + (size_t)(rowTile + rl) * D_IN + g * 8;
  const unsigned char* bspb = (const unsigned char*)bsp;

  // prologue: stage slab 0 (reg->LDS), prefetch A(0)
  uint4 stg0, stg1, stg2, stg3;
  {
    const unsigned char* s0 = bspb + (4 * w) * 1024 + l * 16;
    stg0 = *(const uint4*)(s0);
    stg1 = *(const uint4*)(s0 + 1024);
    stg2 = *(const uint4*)(s0 + 2048);
    stg3 = *(const uint4*)(s0 + 3072);
  }
  float4 a0 = *(const float4*)(xrow);
  float4 a1 = *(const float4*)(xrow + 4);
  float4 a2 = *(const float4*)(xrow + 32);
  float4 a3 = *(const float4*)(xrow + 36);
  {
    unsigned char* dB = &sB[0][(4 * w) * 1024 + l * 16];
    *(uint4*)(dB)        = stg0;
    *(uint4*)(dB + 1024) = stg1;
    *(uint4*)(dB + 2048) = stg2;
    *(uint4*)(dB + 3072) = stg3;
  }
  f32x4 acc[4] = {};
  __syncthreads();

  for (int it = 0; it < NITER; ++it) {
    const int cur = it & 1;
    const int nxt = cur ^ 1;
    const bool more = (it + 1 < NITER);
    float4 n0, n1, n2, n3;
    if (more) {
      const float* pn = xrow + (it + 1) * 64;      // A prefetch (next iter)
      n0 = *(const float4*)(pn);
      n1 = *(const float4*)(pn + 4);
      n2 = *(const float4*)(pn + 32);
      n3 = *(const float4*)(pn + 36);
      const unsigned char* s0 = bspb + (size_t)(it + 1) * SLAB + (4 * w) * 1024 + l * 16;
      stg0 = *(const uint4*)(s0);                  // B stage loads (next iter)
      stg1 = *(const uint4*)(s0 + 1024);
      stg2 = *(const uint4*)(s0 + 2048);
      stg3 = *(const uint4*)(s0 + 3072);
    }
    // compute current buffer: 2 k-halves x 4 n-frags x 3 split terms
#pragma unroll
    for (int h = 0; h < 2; ++h) {
      bf16x8 ahi, alo;
      if (h == 0) cvt_hilo(a0, a1, ahi, alo);
      else        cvt_hilo(a2, a3, ahi, alo);
      const unsigned char* bb = &sB[cur][h * 8192 + l * 16];
#pragma unroll
      for (int f = 0; f < 4; ++f) {
        bf16x8 bh = ldfrag(bb + (f * 2)     * 1024);
        bf16x8 bl = ldfrag(bb + (f * 2 + 1) * 1024);
        acc[f] = __builtin_amdgcn_mfma_f32_16x16x32_bf16(ahi, bh, acc[f], 0, 0, 0);
        acc[f] = __builtin_amdgcn_mfma_f32_16x16x32_bf16(alo, bh, acc[f], 0, 0, 0);
        acc[f] = __builtin_amdgcn_mfma_f32_16x16x32_bf16(ahi, bl, acc[f], 0, 0, 0);
      }
    }
    if (more) {
      unsigned char* dB = &sB[nxt][(4 * w) * 1024 + l * 16];
      *(uint4*)(dB)        = stg0;
      *(uint4*)(dB + 1024) = stg1;
      *(uint4*)(dB + 2048) = stg2;
      *(uint4*)(dB + 3072) = stg3;
      a0 = n0; a1 = n1; a2 = n2; a3 = n3;
    }
    __syncthreads();
  }

  // epilogue: dump C to own wave's strip (no cross-wave use -> no barrier)
#pragma unroll
  for (int f = 0; f < 4; ++f)
#pragma unroll
    for (int r = 0; r < 4; ++r)
      strips[w][4 * g + r][16 * f + rl] = acc[f][r];

  // lane-group g handles trees {g, g+4, g+8, g+12}; row = rl of this wave's tile
  float o0 = 0.0f, o1 = 0.0f;
#pragma unroll
  for (int jt = 0; jt < 4; ++jt) {
    int t = g + 4 * jt;
    if (t < NT) {
      const float* cf = coef + t * 10;
      float dd[4];
#pragma unroll
      for (int i = 0; i < 4; ++i) {
        float z = strips[w][rl][4 * t + i] + bias[4 * t + i];
        dd[i] = 1.0f / (1.0f + __expf(-z));
      }
      float s = 1.0f / (4.0f + dd[3] + 1e-8f);
      o0 += s * (cf[0] + dd[0] * cf[2] + dd[1] * cf[4] + dd[2] * cf[6] + dd[3] * cf[8]);
      o1 += s * (cf[1] + dd[0] * cf[3] + dd[1] * cf[5] + dd[2] * cf[7] + dd[3] * cf[9]);
    }
  }
  o0 += __shfl_xor(o0, 16); o0 += __shfl_xor(o0, 32);
  o1 += __shfl_xor(o1, 16); o1 += __shfl_xor(o1, 32);
  if (l < 16) {
    ((float2*)out)[rowTile + rl] = make_float2(o0, o1);
  }
}

// ---------------- launch -----------------------------------------------------
extern "C" void kernel_launch(void* const* d_in, const int* in_sizes, int n_in,
                              void* d_out, int out_size, void* d_ws, size_t ws_size,
                              hipStream_t stream) {
  (void)in_sizes; (void)n_in; (void)out_size; (void)ws_size;
  const float* x  = (const float*)d_in[0];
  const float* tp = (const float*)d_in[1];
  const float* tw = (const float*)d_in[2];
  float* out = (float*)d_out;

  unsigned short* bsp = (unsigned short*)d_ws;                    // 524288 B
  float* bias = (float*)((char*)d_ws + 524288);                   // 256 B
  float* coef = (float*)((char*)d_ws + 524288 + 256);             // 600 B

  prep_split<<<512, 256, 0, stream>>>(tp, bsp);
  prep_coef<<<1, 64, 0, stream>>>(tp, tw, bias, coef);
  tree_fused<<<512, 256, 0, stream>>>(x, bsp, bias, coef, out);
}